// Round 3
// baseline (492717.920 us; speedup 1.0000x reference)
//
#include <hip/hip_runtime.h>

#define RES      8192
#define IN_DIM   64
#define DYN      1000
#define TOT      2000

#define BLOCKS   512
#define TPB      1024
#define WPB      (TPB / 64)      // 16 waves per block
#define NWAVES   (BLOCKS * WPB)  // 8192 waves -> exactly 1 W_h row per wave

// Output layout (floats):
//   prediction          [     0 ..  63999]
//   target              [ 64000 .. 127999]  copy of input[1000:2000]
//   prediction_augment  [128000 .. 255999]
//   target_augment      [256000 .. 383999]  copy of input
//
// ws layout (float indices), all 128-B aligned:
#define WS_H0     0          // h buffer 0 [8192]
#define WS_H1     8192       // h buffer 1 [8192]
#define WS_OUT    16384      // outbuf [64]
#define WS_PCNT   16448      // producer monotone counter (own line)
#define WS_OFLAG  16480      // outbuf-ready flag (own line)
#define WS_GEN    16512      // barrier generation (own line)
#define WS_SLOTS  16544      // 512 slots, stride 32 floats (128 B each)
#define WS_TOTAL  33024      // floats to zero

__global__ void copy_targets(const float* __restrict__ input, float* __restrict__ out) {
    int i = blockIdx.x * blockDim.x + threadIdx.x;
    if (i < 64000)  out[64000 + i]  = input[64000 + i];   // target
    if (i < 128000) out[256000 + i] = input[i];           // target_augment
}

// Contention-free grid barrier: per-block padded arrival slots (plain stores,
// monotone epoch -> no reset), block 0 wave 0 scans and publishes gen.
// All 512 blocks are co-resident (512 x 1024 = 256 CUs x 2048 threads).
__device__ __forceinline__ void grid_barrier(unsigned* slots, unsigned* gen, unsigned epoch) {
    __syncthreads();
    if (threadIdx.x == 0) {
        __threadfence();  // release: publish this block's h stores
        __hip_atomic_store(&slots[blockIdx.x * 32], epoch,
                           __ATOMIC_RELAXED, __HIP_MEMORY_SCOPE_AGENT);
    }
    if (blockIdx.x == 0) {
        if (threadIdx.x < 64) {
            const int lane = threadIdx.x;
            for (;;) {
                unsigned mn = 0xffffffffu;
                #pragma unroll
                for (int j = 0; j < BLOCKS / 64; ++j) {
                    unsigned v = __hip_atomic_load(&slots[(lane + j * 64) * 32],
                                                   __ATOMIC_RELAXED, __HIP_MEMORY_SCOPE_AGENT);
                    mn = v < mn ? v : mn;
                }
                if (__all((int)(mn >= epoch))) break;
                __builtin_amdgcn_s_sleep(2);
            }
            if (lane == 0) {
                __threadfence();
                __hip_atomic_store(gen, epoch, __ATOMIC_RELAXED, __HIP_MEMORY_SCOPE_AGENT);
            }
        }
    } else {
        if (threadIdx.x == 0) {
            while (__hip_atomic_load(gen, __ATOMIC_RELAXED, __HIP_MEMORY_SCOPE_AGENT) < epoch)
                __builtin_amdgcn_s_sleep(4);
        }
    }
    __threadfence();  // acquire: invalidate stale L1 lines before next step's reads
    __syncthreads();
}

__global__ __launch_bounds__(TPB, 8) void esn_kernel(
    const float* __restrict__ input,   // 2000 x 64
    const float* __restrict__ W_in,    // 8192 x 64
    const float* __restrict__ W_h,     // 8192 x 8192
    const float* __restrict__ W_out,   // 64 x 8192
    float* __restrict__ out,
    float* __restrict__ ws)
{
    __shared__ __align__(16) float h_lds[RES];

    float* hbuf0  = ws + WS_H0;
    float* hbuf1  = ws + WS_H1;
    float* outbuf = ws + WS_OUT;
    unsigned* pcnt  = (unsigned*)(ws + WS_PCNT);
    unsigned* oflag = (unsigned*)(ws + WS_OFLAG);
    unsigned* gen   = (unsigned*)(ws + WS_GEN);
    unsigned* slots = (unsigned*)(ws + WS_SLOTS);

    float* pred    = out;            // prediction
    float* aug_out = out + 128000;   // prediction_augment

    const int tid  = threadIdx.x;
    const int lane = tid & 63;
    const int wid  = tid >> 6;
    const int r    = blockIdx.x * WPB + wid;   // this wave's W_h row (one each)

    for (int t = 0; t < TOT; ++t) {
        const float* hcur = (t & 1) ? hbuf1 : hbuf0;
        float*       hnxt = (t & 1) ? hbuf0 : hbuf1;

        // ---- stage h into LDS (32 KB per block, 2 float4 per thread) ----
        {
            const float4* src = (const float4*)hcur;
            float4*       dst = (float4*)h_lds;
            dst[tid]       = src[tid];
            dst[tid + TPB] = src[tid + TPB];
        }
        __syncthreads();

        // ---- producers: out_t[j] = W_out[j] @ aug(h_t), j = blockIdx < 64, wave 1 ----
        // (wave 1, not wave 0: block 0 wave 0 is the barrier master)
        if (wid == 1 && blockIdx.x < 64 && t >= 1) {
            const int j = blockIdx.x;
            const float* wrow = W_out + (size_t)j * RES;
            float acc = 0.f;
            #pragma unroll 8
            for (int i = 0; i < RES / 256; ++i) {
                const int k = (lane << 2) + (i << 8);
                float4 w = *(const float4*)(wrow + k);
                float4 h = *(const float4*)(h_lds + k);
                // aug: even index -> h*h, odd -> h (k is a multiple of 4)
                acc += w.x * h.x * h.x + w.y * h.y + w.z * h.z * h.z + w.w * h.w;
            }
            #pragma unroll
            for (int off = 32; off; off >>= 1) acc += __shfl_xor(acc, off, 64);
            if (lane == 0) {
                if (t <= DYN)  aug_out[(size_t)(t - 1) * 64 + j] = acc;  // warm_up[t-1]
                if (t >= DYN) {
                    pred[(size_t)(t - DYN) * 64 + j] = acc;              // prediction
                    aug_out[(size_t)t * 64 + j]      = acc;              // aug[1000+s]
                    outbuf[j]                        = acc;              // fed back
                    __threadfence();
                    unsigned old = __hip_atomic_fetch_add(pcnt, 1u,
                                       __ATOMIC_ACQ_REL, __HIP_MEMORY_SCOPE_AGENT);
                    if (old == 64u * (unsigned)(t - DYN + 1) - 1u) {
                        __threadfence();
                        __hip_atomic_store(oflag, (unsigned)(t + 1),
                                           __ATOMIC_RELAXED, __HIP_MEMORY_SCOPE_AGENT);
                    }
                }
            }
        }

        if (t == TOT - 1) break;   // last h-update is never consumed

        // ---- h_{t+1}[r] = tanh(W_in[r] @ x_t + W_h[r] @ h_t), 1 row per wave ----
        {
            const float* wrow = W_h + (size_t)r * RES;
            float a0 = 0.f, a1 = 0.f, a2 = 0.f, a3 = 0.f;
            #pragma unroll 8
            for (int i = 0; i < RES / 256; ++i) {
                const int k = (lane << 2) + (i << 8);
                float4 w = *(const float4*)(wrow + k);
                float4 h = *(const float4*)(h_lds + k);
                a0 += w.x * h.x; a1 += w.y * h.y;
                a2 += w.z * h.z; a3 += w.w * h.w;
            }
            float acc = (a0 + a2) + (a1 + a3);

            // x is only needed in the epilogue: in pred phase, wait for the
            // producer flag AFTER the full dot (overlaps the whole row load).
            float x_l;
            if (t < DYN) {
                x_l = input[(size_t)t * IN_DIM + lane];
            } else {
                while (__hip_atomic_load(oflag, __ATOMIC_RELAXED,
                                         __HIP_MEMORY_SCOPE_AGENT) < (unsigned)(t + 1))
                    __builtin_amdgcn_s_sleep(2);
                __threadfence();  // acquire
                x_l = outbuf[lane];
            }
            acc += W_in[(size_t)r * IN_DIM + lane] * x_l;

            #pragma unroll
            for (int off = 32; off; off >>= 1) acc += __shfl_xor(acc, off, 64);
            if (lane == 0) hnxt[r] = tanhf(acc);
        }

        grid_barrier(slots, gen, (unsigned)(t + 1));
    }
}

extern "C" void kernel_launch(void* const* d_in, const int* in_sizes, int n_in,
                              void* d_out, int out_size, void* d_ws, size_t ws_size,
                              hipStream_t stream) {
    const float* input = (const float*)d_in[0];
    const float* W_in  = (const float*)d_in[1];
    const float* W_h   = (const float*)d_in[2];
    const float* W_out = (const float*)d_in[3];
    float* out = (float*)d_out;
    float* ws  = (float*)d_ws;

    // h buffers / outbuf / flags / barrier slots must start at zero
    hipMemsetAsync(d_ws, 0, WS_TOTAL * sizeof(float), stream);

    copy_targets<<<dim3((128000 + 255) / 256), dim3(256), 0, stream>>>(input, out);

    esn_kernel<<<dim3(BLOCKS), dim3(TPB), 0, stream>>>(input, W_in, W_h, W_out, out, ws);
}

// Round 4
// 119875.073 us; speedup vs baseline: 4.1103x; 4.1103x over previous
//
#include <hip/hip_runtime.h>
#include <stdint.h>

#define RES      8192
#define IN_DIM   64
#define DYN      1000
#define TOT      2000

#define BLOCKS   512
#define TPB      1024
#define WPB      16          // waves per block

// Output layout (floats):
//   prediction          [     0 ..  63999]
//   target              [ 64000 .. 127999]  copy of input[1000:2000]
//   prediction_augment  [128000 .. 255999]
//   target_augment      [256000 .. 383999]  copy of input
//
// ws layout (float indices). All sync lines padded to 128 B (32 floats) so
// pollers never share a line. ALL cross-block traffic uses relaxed agent-scope
// atomics (cache-bypass, served at the coherence point) -> NO fences anywhere.
#define WS_H0     0              // h buffer 0 [8192]
#define WS_H1     8192           // h buffer 1 [8192]
#define WS_OUT    16384          // outbuf [64]
#define WS_DONE   16448          // 64 producer-done slots x 32
#define WS_FLAG   18496          // 32 flag copies x 32
#define WS_GEN    19520          // 32 gen copies x 32
#define WS_SLOT   20544          // 512 arrival slots x 32
#define WS_TOTAL  36928

__global__ void copy_targets(const float* __restrict__ input, float* __restrict__ out) {
    int i = blockIdx.x * blockDim.x + threadIdx.x;
    if (i < 64000)  out[64000 + i]  = input[64000 + i];   // target
    if (i < 128000) out[256000 + i] = input[i];           // target_augment
}

__device__ __forceinline__ unsigned ld_u32(const unsigned* p) {
    return __hip_atomic_load(p, __ATOMIC_RELAXED, __HIP_MEMORY_SCOPE_AGENT);
}
__device__ __forceinline__ void st_u32(unsigned* p, unsigned v) {
    __hip_atomic_store(p, v, __ATOMIC_RELAXED, __HIP_MEMORY_SCOPE_AGENT);
}
__device__ __forceinline__ float ld_f32(const float* p) {
    return __hip_atomic_load(p, __ATOMIC_RELAXED, __HIP_MEMORY_SCOPE_AGENT);
}
__device__ __forceinline__ void st_f32(float* p, float v) {
    __hip_atomic_store(p, v, __ATOMIC_RELAXED, __HIP_MEMORY_SCOPE_AGENT);
}
__device__ __forceinline__ uint64_t ld_u64(const uint64_t* p) {
    return __hip_atomic_load(p, __ATOMIC_RELAXED, __HIP_MEMORY_SCOPE_AGENT);
}

__global__ __launch_bounds__(TPB, 8) void esn_kernel(
    const float* __restrict__ input,   // 2000 x 64
    const float* __restrict__ W_in,    // 8192 x 64
    const float* __restrict__ W_h,     // 8192 x 8192
    const float* __restrict__ W_out,   // 64 x 8192
    float* __restrict__ out,
    float* __restrict__ ws)
{
    __shared__ __align__(16) float h_lds[RES];
    __shared__ float xbuf[IN_DIM];

    float*    hbuf0 = ws + WS_H0;
    float*    hbuf1 = ws + WS_H1;
    float*    outbuf = ws + WS_OUT;
    unsigned* done  = (unsigned*)(ws + WS_DONE);
    unsigned* flag  = (unsigned*)(ws + WS_FLAG);
    unsigned* gen   = (unsigned*)(ws + WS_GEN);
    unsigned* slot  = (unsigned*)(ws + WS_SLOT);

    float* pred    = out;            // prediction
    float* aug_out = out + 128000;   // prediction_augment

    const int tid  = threadIdx.x;
    const int lane = tid & 63;
    const int wid  = tid >> 6;
    const int bid  = blockIdx.x;
    const int r    = bid * WPB + wid;          // this wave's W_h row

    for (int t = 0; t < TOT; ++t) {
        const float* hcur = (t & 1) ? hbuf1 : hbuf0;
        float*       hnxt = (t & 1) ? hbuf0 : hbuf1;

        // ---- stage h_t into LDS via cache-bypass loads (always-fresh) ----
        {
            const uint64_t* src = (const uint64_t*)hcur;
            uint64_t*       dst = (uint64_t*)h_lds;
            #pragma unroll
            for (int i = 0; i < RES / 2 / TPB; ++i)          // 4 x u64 per thread
                dst[tid + i * TPB] = ld_u64(src + tid + i * TPB);
        }
        __syncthreads();

        // ---- producers: out_t[j] = W_out[j] @ aug(h_t), wave 1 of blocks 0..63 ----
        if (wid == 1 && bid < 64 && t >= 1) {
            const int j = bid;
            const float* wrow = W_out + (size_t)j * RES;
            float acc = 0.f;
            #pragma unroll 8
            for (int i = 0; i < RES / 256; ++i) {
                const int k = (lane << 2) + (i << 8);
                float4 w = *(const float4*)(wrow + k);
                float4 h = *(const float4*)(h_lds + k);
                // aug: even index -> h*h, odd -> h (k is a multiple of 4)
                acc += w.x * h.x * h.x + w.y * h.y + w.z * h.z * h.z + w.w * h.w;
            }
            #pragma unroll
            for (int off = 32; off; off >>= 1) acc += __shfl_xor(acc, off, 64);
            if (lane == 0) {
                if (t <= DYN)  aug_out[(size_t)(t - 1) * 64 + j] = acc;  // warm_up[t-1]
                if (t >= DYN) {
                    pred[(size_t)(t - DYN) * 64 + j] = acc;              // prediction
                    aug_out[(size_t)t * 64 + j]      = acc;              // aug[t]
                    st_f32(outbuf + j, acc);                             // fed back
                    __builtin_amdgcn_s_waitcnt(0);      // outbuf visible before done
                    st_u32(done + j * 32, (unsigned)(t - DYN + 1));
                }
            }
        }

        // ---- aggregator: wave 0 of block 64 collects the 64 done slots and
        //      fans the ready-flag out to 32 padded copies (16 pollers each) ----
        if (wid == 0 && bid == 64 && t >= DYN && t < TOT - 1) {
            const unsigned p = (unsigned)(t - DYN + 1);
            for (;;) {
                unsigned v = ld_u32(done + lane * 32);    // 64 distinct lines
                if (__all((int)(v >= p))) break;
                __builtin_amdgcn_s_sleep(2);
            }
            __builtin_amdgcn_s_waitcnt(0);
            if (lane < 32) st_u32(flag + lane * 32, p);
        }

        if (t == TOT - 1) break;   // last h-update is never consumed

        // ---- h_{t+1}[r] = tanh(W_in[r] @ x_t + W_h[r] @ h_t) ----
        {
            const float* wrow = W_h + (size_t)r * RES;
            float a0 = 0.f, a1 = 0.f, a2 = 0.f, a3 = 0.f;
            #pragma unroll 8
            for (int i = 0; i < RES / 256; ++i) {
                const int k = (lane << 2) + (i << 8);
                float4 w = *(const float4*)(wrow + k);
                float4 h = *(const float4*)(h_lds + k);
                a0 += w.x * h.x; a1 += w.y * h.y;
                a2 += w.z * h.z; a3 += w.w * h.w;
            }
            float acc = (a0 + a2) + (a1 + a3);

            // x only needed now: warm -> input row; pred -> wait for flag
            // (overlapped with the whole W_h row load above), thread 0 polls.
            float x_l;
            if (t < DYN) {
                x_l = input[(size_t)t * IN_DIM + lane];
            } else {
                const unsigned p = (unsigned)(t - DYN + 1);
                __syncthreads();
                if (tid == 0) {
                    while (ld_u32(flag + (bid & 31) * 32) < p)
                        __builtin_amdgcn_s_sleep(2);
                }
                __syncthreads();
                if (tid < IN_DIM) xbuf[tid] = ld_f32(outbuf + tid);
                __syncthreads();
                x_l = xbuf[lane];
            }
            acc += W_in[(size_t)r * IN_DIM + lane] * x_l;

            #pragma unroll
            for (int off = 32; off; off >>= 1) acc += __shfl_xor(acc, off, 64);
            if (lane == 0) st_f32(hnxt + r, tanhf(acc));
        }

        // ---- grid barrier: drain own stores, per-block slot store (no RMW),
        //      block 0 scans 512 distinct lines, fans gen out to 32 copies ----
        __builtin_amdgcn_s_waitcnt(0);    // per-wave: h store is at coherence point
        __syncthreads();                  // all 16 waves drained
        const unsigned e = (unsigned)(t + 1);
        if (tid == 0) st_u32(slot + bid * 32, e);
        if (bid == 0) {
            unsigned v = e;
            for (;;) {
                if (tid < BLOCKS) v = ld_u32(slot + tid * 32);
                if (__syncthreads_and(tid >= BLOCKS || v >= e)) break;
                __builtin_amdgcn_s_sleep(2);
            }
            if (tid < 32) st_u32(gen + tid * 32, e);
        } else {
            if (tid == 0) {
                while (ld_u32(gen + (bid & 31) * 32) < e)
                    __builtin_amdgcn_s_sleep(4);
            }
            __syncthreads();
        }
    }
}

extern "C" void kernel_launch(void* const* d_in, const int* in_sizes, int n_in,
                              void* d_out, int out_size, void* d_ws, size_t ws_size,
                              hipStream_t stream) {
    const float* input = (const float*)d_in[0];
    const float* W_in  = (const float*)d_in[1];
    const float* W_h   = (const float*)d_in[2];
    const float* W_out = (const float*)d_in[3];
    float* out = (float*)d_out;
    float* ws  = (float*)d_ws;

    // h buffers / outbuf / all sync lines must start at zero (ws is poisoned)
    hipMemsetAsync(d_ws, 0, WS_TOTAL * sizeof(float), stream);

    copy_targets<<<dim3((128000 + 255) / 256), dim3(256), 0, stream>>>(input, out);

    esn_kernel<<<dim3(BLOCKS), dim3(TPB), 0, stream>>>(input, W_in, W_h, W_out, out, ws);
}

// Round 5
// 73984.186 us; speedup vs baseline: 6.6598x; 1.6203x over previous
//
#include <hip/hip_runtime.h>
#include <hip/hip_fp16.h>
#include <stdint.h>

#define RES      8192
#define IN_DIM   64
#define DYN      1000
#define TOT      2000

#define BLOCKS   512
#define TPB      1024
#define WPB      16          // waves per block

// Output layout (floats):
//   prediction          [     0 ..  63999]
//   target              [ 64000 .. 127999]  copy of input[1000:2000]
//   prediction_augment  [128000 .. 255999]
//   target_augment      [256000 .. 383999]  copy of input
//
// ws layout (float indices). Sync lines padded to 128 B. ALL cross-block
// traffic uses relaxed agent-scope atomics (cache-bypass, coherence-point
// served) -> no fences, no L2 invalidates anywhere.
#define WS_H0     0              // h buffer 0 [8192]
#define WS_H1     8192           // h buffer 1 [8192]
#define WS_OUT    16384          // outbuf [64]
#define WS_DONE   16448          // 64 producer-done slots x 32
#define WS_FLAG   18496          // 32 flag copies x 32
#define WS_GEN    19520          // 32 gen copies x 32
#define WS_SLOT   20544          // 512 arrival slots x 32
#define WS_TOTAL  36928          // floats to zero
#define WS_WH16   40960          // fp16 W_h starts here (float index; 16-B aligned)

__global__ void copy_targets(const float* __restrict__ input, float* __restrict__ out) {
    int i = blockIdx.x * blockDim.x + threadIdx.x;
    if (i < 64000)  out[64000 + i]  = input[64000 + i];   // target
    if (i < 128000) out[256000 + i] = input[i];           // target_augment
}

// fp32 -> fp16 conversion of W_h (67.1M elems). ~384 MiB of traffic, ~75 us.
__global__ void convert_wh(const float* __restrict__ W_h, __half2* __restrict__ w16) {
    const float4* src = (const float4*)W_h;
    const int stride = gridDim.x * blockDim.x;
    for (int j = blockIdx.x * blockDim.x + threadIdx.x;
         j < RES * RES / 4; j += stride) {
        float4 v = src[j];
        w16[2 * j]     = __floats2half2_rn(v.x, v.y);
        w16[2 * j + 1] = __floats2half2_rn(v.z, v.w);
    }
}

__device__ __forceinline__ unsigned ld_u32(const unsigned* p) {
    return __hip_atomic_load(p, __ATOMIC_RELAXED, __HIP_MEMORY_SCOPE_AGENT);
}
__device__ __forceinline__ void st_u32(unsigned* p, unsigned v) {
    __hip_atomic_store(p, v, __ATOMIC_RELAXED, __HIP_MEMORY_SCOPE_AGENT);
}
__device__ __forceinline__ float ld_f32(const float* p) {
    return __hip_atomic_load(p, __ATOMIC_RELAXED, __HIP_MEMORY_SCOPE_AGENT);
}
__device__ __forceinline__ void st_f32(float* p, float v) {
    __hip_atomic_store(p, v, __ATOMIC_RELAXED, __HIP_MEMORY_SCOPE_AGENT);
}
__device__ __forceinline__ uint64_t ld_u64(const uint64_t* p) {
    return __hip_atomic_load(p, __ATOMIC_RELAXED, __HIP_MEMORY_SCOPE_AGENT);
}

template <bool FP16>
__global__ __launch_bounds__(TPB, 8) void esn_kernel(
    const float* __restrict__ input,   // 2000 x 64
    const float* __restrict__ W_in,    // 8192 x 64
    const float* __restrict__ W_h,     // 8192 x 8192 (fp32, used when !FP16)
    const float* __restrict__ W_out,   // 64 x 8192
    float* __restrict__ out,
    float* __restrict__ ws)
{
    __shared__ __align__(16) float h_lds[RES];
    __shared__ float xbuf[IN_DIM];

    float*    hbuf0  = ws + WS_H0;
    float*    hbuf1  = ws + WS_H1;
    float*    outbuf = ws + WS_OUT;
    unsigned* done   = (unsigned*)(ws + WS_DONE);
    unsigned* flag   = (unsigned*)(ws + WS_FLAG);
    unsigned* gen    = (unsigned*)(ws + WS_GEN);
    unsigned* slot   = (unsigned*)(ws + WS_SLOT);
    const __half2* wh16 = (const __half2*)(ws + WS_WH16);

    float* pred    = out;            // prediction
    float* aug_out = out + 128000;   // prediction_augment

    const int tid  = threadIdx.x;
    const int lane = tid & 63;
    const int wid  = tid >> 6;
    const int bid  = blockIdx.x;
    const int r    = bid * WPB + wid;          // this wave's W_h row

    for (int t = 0; t < TOT; ++t) {
        const float* hcur = (t & 1) ? hbuf1 : hbuf0;
        float*       hnxt = (t & 1) ? hbuf0 : hbuf1;

        // ---- stage h_t into LDS via cache-bypass loads (always-fresh) ----
        {
            const uint64_t* src = (const uint64_t*)hcur;
            uint64_t*       dst = (uint64_t*)h_lds;
            #pragma unroll
            for (int i = 0; i < RES / 2 / TPB; ++i)
                dst[tid + i * TPB] = ld_u64(src + tid + i * TPB);
        }
        __syncthreads();

        // ---- producers: out_t[j] = W_out[j] @ aug(h_t), wave 1 of blocks 0..63 ----
        if (wid == 1 && bid < 64 && t >= 1) {
            const int j = bid;
            const float* wrow = W_out + (size_t)j * RES;
            float acc = 0.f;
            #pragma unroll 8
            for (int i = 0; i < RES / 256; ++i) {
                const int k = (lane << 2) + (i << 8);
                float4 w = *(const float4*)(wrow + k);
                float4 h = *(const float4*)(h_lds + k);
                // aug: even index -> h*h, odd -> h (k is a multiple of 4)
                acc += w.x * h.x * h.x + w.y * h.y + w.z * h.z * h.z + w.w * h.w;
            }
            #pragma unroll
            for (int off = 32; off; off >>= 1) acc += __shfl_xor(acc, off, 64);
            if (lane == 0) {
                if (t <= DYN)  aug_out[(size_t)(t - 1) * 64 + j] = acc;  // warm_up[t-1]
                if (t >= DYN) {
                    pred[(size_t)(t - DYN) * 64 + j] = acc;              // prediction
                    aug_out[(size_t)t * 64 + j]      = acc;              // aug[t]
                    st_f32(outbuf + j, acc);                             // fed back
                    __builtin_amdgcn_s_waitcnt(0);      // outbuf visible before done
                    st_u32(done + j * 32, (unsigned)(t - DYN + 1));
                }
            }
        }

        // ---- aggregator: wave 0 of block 64 collects done slots, fans flag out ----
        if (wid == 0 && bid == 64 && t >= DYN && t < TOT - 1) {
            const unsigned p = (unsigned)(t - DYN + 1);
            for (;;) {
                unsigned v = ld_u32(done + lane * 32);    // 64 distinct lines
                if (__all((int)(v >= p))) break;
                __builtin_amdgcn_s_sleep(2);
            }
            __builtin_amdgcn_s_waitcnt(0);
            if (lane < 32) st_u32(flag + lane * 32, p);
        }

        if (t == TOT - 1) break;   // last h-update is never consumed

        // ---- h_{t+1}[r] = tanh(W_in[r] @ x_t + W_h[r] @ h_t) ----
        {
            float a0 = 0.f, a1 = 0.f, a2 = 0.f, a3 = 0.f;
            if (FP16) {
                const __half2* wrow = wh16 + (size_t)r * (RES / 2);
                #pragma unroll 8
                for (int i = 0; i < RES / 512; ++i) {
                    // k indexes half2; lane covers 4 half2 = 8 elems = 16 B
                    const int k = (lane << 2) + (i << 8);
                    const __half2 w0 = wrow[k + 0];
                    const __half2 w1 = wrow[k + 1];
                    const __half2 w2 = wrow[k + 2];
                    const __half2 w3 = wrow[k + 3];
                    float4 hA = *(const float4*)(h_lds + 2 * k);
                    float4 hB = *(const float4*)(h_lds + 2 * k + 4);
                    float2 f0 = __half22float2(w0);
                    float2 f1 = __half22float2(w1);
                    float2 f2 = __half22float2(w2);
                    float2 f3 = __half22float2(w3);
                    a0 += f0.x * hA.x; a1 += f0.y * hA.y;
                    a2 += f1.x * hA.z; a3 += f1.y * hA.w;
                    a0 += f2.x * hB.x; a1 += f2.y * hB.y;
                    a2 += f3.x * hB.z; a3 += f3.y * hB.w;
                }
            } else {
                const float* wrow = W_h + (size_t)r * RES;
                #pragma unroll 8
                for (int i = 0; i < RES / 256; ++i) {
                    const int k = (lane << 2) + (i << 8);
                    float4 w = *(const float4*)(wrow + k);
                    float4 h = *(const float4*)(h_lds + k);
                    a0 += w.x * h.x; a1 += w.y * h.y;
                    a2 += w.z * h.z; a3 += w.w * h.w;
                }
            }
            float acc = (a0 + a2) + (a1 + a3);

            // x only needed now: warm -> input row; pred -> wait for flag
            // (overlapped with the whole W_h row load above), thread 0 polls.
            float x_l;
            if (t < DYN) {
                x_l = input[(size_t)t * IN_DIM + lane];
            } else {
                const unsigned p = (unsigned)(t - DYN + 1);
                __syncthreads();
                if (tid == 0) {
                    while (ld_u32(flag + (bid & 31) * 32) < p)
                        __builtin_amdgcn_s_sleep(2);
                }
                __syncthreads();
                if (tid < IN_DIM) xbuf[tid] = ld_f32(outbuf + tid);
                __syncthreads();
                x_l = xbuf[lane];
            }
            acc += W_in[(size_t)r * IN_DIM + lane] * x_l;

            #pragma unroll
            for (int off = 32; off; off >>= 1) acc += __shfl_xor(acc, off, 64);
            if (lane == 0) st_f32(hnxt + r, tanhf(acc));
        }

        // ---- grid barrier: drain own stores, per-block slot store (no RMW),
        //      block 0 scans 512 distinct lines, fans gen out to 32 copies ----
        __builtin_amdgcn_s_waitcnt(0);
        __syncthreads();
        const unsigned e = (unsigned)(t + 1);
        if (tid == 0) st_u32(slot + bid * 32, e);
        if (bid == 0) {
            unsigned v = e;
            for (;;) {
                if (tid < BLOCKS) v = ld_u32(slot + tid * 32);
                if (__syncthreads_and(tid >= BLOCKS || v >= e)) break;
                __builtin_amdgcn_s_sleep(2);
            }
            if (tid < 32) st_u32(gen + tid * 32, e);
        } else {
            if (tid == 0) {
                while (ld_u32(gen + (bid & 31) * 32) < e)
                    __builtin_amdgcn_s_sleep(4);
            }
            __syncthreads();
        }
    }
}

extern "C" void kernel_launch(void* const* d_in, const int* in_sizes, int n_in,
                              void* d_out, int out_size, void* d_ws, size_t ws_size,
                              hipStream_t stream) {
    const float* input = (const float*)d_in[0];
    const float* W_in  = (const float*)d_in[1];
    const float* W_h   = (const float*)d_in[2];
    const float* W_out = (const float*)d_in[3];
    float* out = (float*)d_out;
    float* ws  = (float*)d_ws;

    // sync area + h buffers must start at zero (ws is poisoned 0xAA each call)
    hipMemsetAsync(d_ws, 0, WS_TOTAL * sizeof(float), stream);

    copy_targets<<<dim3((128000 + 255) / 256), dim3(256), 0, stream>>>(input, out);

    const size_t need = (size_t)WS_WH16 * sizeof(float)
                      + (size_t)RES * RES * sizeof(__half);
    if (ws_size >= need) {
        // fp16 W_h (128 MiB -> fully Infinity-Cache-resident)
        convert_wh<<<dim3(2048), dim3(1024), 0, stream>>>(
            W_h, (__half2*)(ws + WS_WH16));
        esn_kernel<true><<<dim3(BLOCKS), dim3(TPB), 0, stream>>>(
            input, W_in, W_h, W_out, out, ws);
    } else {
        // fallback: fp32 path (round-4 behavior)
        esn_kernel<false><<<dim3(BLOCKS), dim3(TPB), 0, stream>>>(
            input, W_in, W_h, W_out, out, ws);
    }
}